// Round 15
// baseline (60.484 us; speedup 1.0000x reference)
//
#include <hip/hip_runtime.h>
#include <hip/hip_fp16.h>

#define HH 256
#define WW 256
#define HWSZ (HH*WW)
#define CC 64
#define GG 4
#define GC 16
#define KK 3
#define PP 9
#define NB 2
#define NBG (NB*GG)            // 8 (b,g) slices
#define NBLK_RP (NBG*HH)       // 2048 repack blocks
#define NBLK_MAIN (NBG*1024)   // 8192 main blocks (16x4 pixel tile x 4 lanes)
#define RW 32                  // staged region width  (32B fp16 pixel-groups)
#define RH 18                  // staged region height
#define RC (RW*RH)             // 576 cells x 32B = 18432 B

typedef float f32x4 __attribute__((ext_vector_type(4)));

// ---------- Kernel 1: planar fp32 -> channels-last fp16 (per (b,g): [y][x][16]) ----------
__global__ __launch_bounds__(256) void repack_kernel(
    const float* __restrict__ img, __half* __restrict__ pk)
{
    int bid = blockIdx.x;
    int y  = bid & (HH - 1);
    int bg = bid >> 8;
    int g  = bg & (GG - 1);
    int b  = bg >> 2;
    int x  = threadIdx.x;

    const float* src = img + (size_t)(b*CC + g*GC) * HWSZ + y*WW + x;
    float v[GC];
#pragma unroll
    for (int c = 0; c < GC; ++c) v[c] = src[c*HWSZ];

    __half2 hh[8];
#pragma unroll
    for (int i = 0; i < 8; ++i) hh[i] = __floats2half2_rn(v[2*i], v[2*i+1]);

    uint4* dst = (uint4*)(pk + ((size_t)bg*HWSZ + y*WW + x) * GC);
    dst[0] = *(uint4*)&hh[0];
    dst[1] = *(uint4*)&hh[4];
}

// ---------- Kernel 2: LDS-staged fp16 region + swizzled ds_read sampling ----------
// r13's wall: ~2.1cyc/64B-segment at the TA (18 gathers x ~24 segs). Bypass:
// stage the tile's 32x18-group region (18KB fp16) in LDS via coalesced fills
// from the L2-resident packed buffer; per-corner reads become ds_read_b128.
// r12 failure modes fixed: fp16 halves LDS (31.5KB total -> 4 blocks/CU) and
// XOR swizzle addr^=(ry&3)<<5 makes bank quadrant (cx^ry)&3 (~2-way, free).
// Out-of-region rows (P~1e-6) use a flagged global fallback (r13-style 64B
// window; ws has 1MB slack so OOB reads see finite 0xAAAA fp16 x weight 0).
__global__ __launch_bounds__(256, 4) void misc_filter_coop(
    const __half* __restrict__ pk,
    const float* __restrict__ kv,
    const float* __restrict__ kh,
    const float* __restrict__ off,
    const float* __restrict__ wgt,
    float* __restrict__ out)
{
    // XCD swizzle: 8192 blocks / 8 XCDs -> each XCD exactly one (b,g) slice.
    int phys = blockIdx.x;
    int logical = (phys & 7) * (NBLK_MAIN / 8) + (phys >> 3);
    int bg  = logical >> 10;          // 1024 tiles per (b,g)
    int blk = logical & 1023;
    int g   = bg & (GG - 1);
    int b   = bg >> 2;

    // 16x4 tile
    int tx = blk & 15;
    int ty = blk >> 4;
    const int tilebase = ty*4*WW + tx*16;
    const int rx0 = tx*16 - 7;        // region x origin (groups)
    const int ry0 = ty*4  - 7;        // region y origin (rows)

    int t  = threadIdx.x;

    __shared__ uint4 stage[RC*2];       // 18432 B fp16 region (XOR-swizzled)
    __shared__ float Wlds[PP][64][4];   // folded lane weights
    __shared__ int   Olds[PP][64][2];   // packed row offsets (row0, row1)

    const __half* pkb = pk + (size_t)bg * HWSZ * GC;   // wave-uniform base

    // ---- stage fill: 576 cells x 2 halves = 1152 coalesced 16B copies ----
    for (int j = t; j < RC*2; j += 256) {
        int cell = j >> 1, half = j & 1;
        int ryc = cell >> 5;           // cell / RW (RW=32)
        int cx  = cell & 31;
        int gx = min(max(rx0 + cx, 0), WW-1);
        int gy = min(max(ry0 + ryc, 0), HH-1);
        const uint4* src = (const uint4*)((const char*)pkb + (gy*WW + gx)*32 + half*16);
        unsigned saddr = ((unsigned)(cell*32) ^ (((unsigned)ryc & 3u) << 5)) + half*16;
        *(uint4*)((char*)stage + saddr) = *src;
    }

    const float* offb = off + (size_t)(b*GG*PP*2 + g*PP*2) * HWSZ + tilebase;
    const float* wgtb = wgt + (size_t)(b*GG*PP   + g*PP  ) * HWSZ + tilebase;
    const float* khb  = kh  + (size_t)(b*GG*KK   + g*KK  ) * HWSZ + tilebase;
    const float* kvb  = kv  + (size_t)(b*KK) * HWSZ + tilebase;

    // ---- Phase 1: per-(pixel,tap) math, once, -> LDS ----
    for (int j = t; j < 64*PP; j += 256) {
        int pidx = j & 63;
        int col  = j & 15;
        int row  = (j >> 4) & 3;
        int tap  = j >> 6;
        int kx   = (tap * 11) >> 5;         // tap/3 for tap<9
        int ky   = tap - 3*kx;
        int pixoff = row*WW + col;
        int pixel1 = tilebase + pixoff;
        int yy = pixel1 >> 8;
        int xx = pixel1 & (WW - 1);

        float ox  = offb[(2*tap  )*HWSZ + pixoff];
        float oy  = offb[(2*tap+1)*HWSZ + pixoff];
        float wv  = wgtb[tap*HWSZ + pixoff];
        float khv = khb[kx*HWSZ + pixoff];
        float kvv = kvb[ky*HWSZ + pixoff];
        float wp  = wv * (khv * kvv);

        float ux = (float)(xx + kx - 1) + ox;
        float uy = (float)(yy + ky - 1) + oy;
        float fx = floorf(ux), fy = floorf(uy);
        float wx = ux - fx,    wy = uy - fy;
        int x0 = (int)fx, y0 = (int)fy;
        int x1 = x0 + 1,  y1 = y0 + 1;
        bool vx0 = (unsigned)x0 < (unsigned)WW;
        bool vx1 = (unsigned)x1 < (unsigned)WW;
        bool vy0 = (unsigned)y0 < (unsigned)HH;
        bool vy1 = (unsigned)y1 < (unsigned)HH;

        float ql = vx0 ? (1.f - wx) : (vx1 ? wx : 0.f);
        float qr = (vx0 && vx1) ? wx : 0.f;
        int   xb = vx0 ? x0 : (vx1 ? x1 : 0);
        float wy0 = vy0 ? (1.f - wy) : 0.f;
        float wy1 = vy1 ? wy : 0.f;
        int y0c = min(max(y0, 0), HH-1);
        int y1c = min(max(y1, 0), HH-1);

        // pack per row: in-region -> cell*32 | (ry&3); else flag | global byte off
        int ix  = xb - rx0;
        int iy0 = y0c - ry0;
        int iy1 = y1c - ry0;
        bool inx = (unsigned)ix < (unsigned)(RW-1);   // need cells ix, ix+1
        int o0 = (inx && (unsigned)iy0 < (unsigned)RH)
               ? (((iy0 << 5) + ix) * 32 | (iy0 & 3))
               : (int)(0x80000000u | (unsigned)((y0c*WW + xb)*32));
        int o1 = (inx && (unsigned)iy1 < (unsigned)RH)
               ? (((iy1 << 5) + ix) * 32 | (iy1 & 3))
               : (int)(0x80000000u | (unsigned)((y1c*WW + xb)*32));

        *(float4*)&Wlds[tap][pidx][0] = make_float4(wy0*ql*wp, wy0*qr*wp,
                                                    wy1*ql*wp, wy1*qr*wp);
        *(int2*)&Olds[tap][pidx][0]   = make_int2(o0, o1);
    }
    __syncthreads();

    // ---- Phase 2: swizzled LDS bilinear reads + mixed fp16/fp32 FMA ----
    int q  = t & 3;                   // lane role: (x-side = q>>1, ch-half = q&1)
    int pi = t >> 2;                  // pixel within tile [0,64)
    int pixel = tilebase + (pi >> 4)*WW + (pi & 15);

    const char* sb = (const char*)&stage[0];
    const char* pg = (const char*)pkb;
    const unsigned qcell = (unsigned)(q >> 1) * 32u;   // which of the 2 cells
    const unsigned qhalf = (unsigned)(q & 1) * 16u;    // which 16B of the cell

    float a0=0.f,a1=0.f,a2=0.f,a3=0.f,a4=0.f,a5=0.f,a6=0.f,a7=0.f;

#define LDSCORNER(v_, o_) do {                                                  \
    unsigned base_ = (unsigned)(o_) & ~3u;                                      \
    unsigned xorv_ = ((unsigned)(o_) & 3u) << 5;                                \
    v_ = *(const uint4*)(sb + (((base_ + qcell) ^ xorv_) + qhalf));             \
    if (__builtin_expect((o_) < 0, 0))                                          \
        v_ = *(const uint4*)(pg + (((o_) & 0x7FFFFFFF) + (unsigned)q*16u));     \
} while (0)

#define FMA8(u_, w_) do {                                                       \
    const __half2* h2_ = (const __half2*)&(u_);                                 \
    float2 f0_ = __half22float2(h2_[0]);                                        \
    float2 f1_ = __half22float2(h2_[1]);                                        \
    float2 f2_ = __half22float2(h2_[2]);                                        \
    float2 f3_ = __half22float2(h2_[3]);                                        \
    a0 = fmaf(f0_.x, (w_), a0); a1 = fmaf(f0_.y, (w_), a1);                     \
    a2 = fmaf(f1_.x, (w_), a2); a3 = fmaf(f1_.y, (w_), a3);                     \
    a4 = fmaf(f2_.x, (w_), a4); a5 = fmaf(f2_.y, (w_), a5);                     \
    a6 = fmaf(f3_.x, (w_), a6); a7 = fmaf(f3_.y, (w_), a7);                     \
} while (0)

#pragma unroll
    for (int p = 0; p < PP; ++p) {
        f32x4 f = *(const f32x4*)&Wlds[p][pi][0];
        int2  o = *(const int2*)&Olds[p][pi][0];
        float wA = (q & 2) ? f[1] : f[0];
        float wB = (q & 2) ? f[3] : f[2];
        uint4 v0, v1;
        LDSCORNER(v0, o.x);
        LDSCORNER(v1, o.y);
        FMA8(v0, wA);
        FMA8(v1, wB);
    }

#undef LDSCORNER
#undef FMA8

    // combine x-corner partials: lanes q and q^2 hold the same 8 channels
    a0 += __shfl_xor(a0, 2); a1 += __shfl_xor(a1, 2);
    a2 += __shfl_xor(a2, 2); a3 += __shfl_xor(a3, 2);
    a4 += __shfl_xor(a4, 2); a5 += __shfl_xor(a5, 2);
    a6 += __shfl_xor(a6, 2); a7 += __shfl_xor(a7, 2);

    float* outp = out + (size_t)(b*CC + g*GC + (q&1)*8 + ((q&2)?4:0)) * HWSZ + pixel;
    if (q & 2) {
        outp[0*HWSZ] = a4; outp[1*HWSZ] = a5; outp[2*HWSZ] = a6; outp[3*HWSZ] = a7;
    } else {
        outp[0*HWSZ] = a0; outp[1*HWSZ] = a1; outp[2*HWSZ] = a2; outp[3*HWSZ] = a3;
    }
}

// ---------- Fallback: direct planar fp32 kernel (if ws too small) ----------
__global__ __launch_bounds__(256) void misc_filter_direct(
    const float* __restrict__ img,
    const float* __restrict__ kv,
    const float* __restrict__ kh,
    const float* __restrict__ off,
    const float* __restrict__ wgt,
    float* __restrict__ out)
{
    int phys = blockIdx.x;
    int logical = (phys & 7) * (NBLK_RP / 8) + (phys >> 3);
    int y  = logical & (HH - 1);
    int bg = logical >> 8;
    int g  = bg & (GG - 1);
    int b  = bg >> 2;
    int x  = threadIdx.x;

    const float* imgp = img + (size_t)(b*CC + g*GC) * HWSZ;
    int pix = y*WW + x;
    const float* offp = off + (size_t)(b*GG*PP*2 + g*PP*2) * HWSZ + pix;
    const float* wgtp = wgt + (size_t)(b*GG*PP   + g*PP  ) * HWSZ + pix;
    const float* khp  = kh  + (size_t)(b*GG*KK   + g*KK  ) * HWSZ + pix;
    const float* kvp  = kv  + (size_t)(b*KK) * HWSZ + pix;

    float khr[KK], kvr[KK];
#pragma unroll
    for (int i = 0; i < KK; ++i) { khr[i] = khp[i*HWSZ]; kvr[i] = kvp[i*HWSZ]; }
    float acc[GC];
#pragma unroll
    for (int c = 0; c < GC; ++c) acc[c] = 0.f;

#pragma unroll
    for (int p = 0; p < PP; ++p) {
        const int kx = p / KK, ky = p % KK;
        float ox = offp[(2*p  )*HWSZ];
        float oy = offp[(2*p+1)*HWSZ];
        float wp = wgtp[p*HWSZ] * khr[kx] * kvr[ky];
        float ux = (float)(x + kx - 1) + ox;
        float uy = (float)(y + ky - 1) + oy;
        float fx = floorf(ux), fy = floorf(uy);
        float wx = ux - fx,    wy = uy - fy;
        int x0 = (int)fx, y0 = (int)fy;
        int x1 = x0 + 1,  y1 = y0 + 1;
        bool vx0 = (unsigned)x0 < (unsigned)WW;
        bool vx1 = (unsigned)x1 < (unsigned)WW;
        bool vy0 = (unsigned)y0 < (unsigned)HH;
        bool vy1 = (unsigned)y1 < (unsigned)HH;
        float w00 = (1.f-wx)*(1.f-wy)*wp; if (!(vx0 && vy0)) w00 = 0.f;
        float w01 =      wx *(1.f-wy)*wp; if (!(vx1 && vy0)) w01 = 0.f;
        float w10 = (1.f-wx)*     wy *wp; if (!(vx0 && vy1)) w10 = 0.f;
        float w11 =      wx *     wy *wp; if (!(vx1 && vy1)) w11 = 0.f;
        int x0c = min(max(x0, 0), WW-1), x1c = min(max(x1, 0), WW-1);
        int y0c = min(max(y0, 0), HH-1), y1c = min(max(y1, 0), HH-1);
        int i00 = y0c*WW + x0c, i01 = y0c*WW + x1c;
        int i10 = y1c*WW + x0c, i11 = y1c*WW + x1c;
#pragma unroll
        for (int c = 0; c < GC; ++c) {
            const float* pl = imgp + c*HWSZ;
            acc[c] = fmaf(w00, pl[i00], acc[c]);
            acc[c] = fmaf(w01, pl[i01], acc[c]);
            acc[c] = fmaf(w10, pl[i10], acc[c]);
            acc[c] = fmaf(w11, pl[i11], acc[c]);
        }
    }
    float* outp = out + (size_t)(b*CC + g*GC) * HWSZ + pix;
#pragma unroll
    for (int c = 0; c < GC; ++c) outp[c*HWSZ] = acc[c];
}

extern "C" void kernel_launch(void* const* d_in, const int* in_sizes, int n_in,
                              void* d_out, int out_size, void* d_ws, size_t ws_size,
                              hipStream_t stream) {
    const float* img = (const float*)d_in[0];
    const float* kv  = (const float*)d_in[1];
    const float* kh  = (const float*)d_in[2];
    const float* off = (const float*)d_in[3];
    const float* wgt = (const float*)d_in[4];
    float* out = (float*)d_out;

    // fp16 packed slices (16.8MB) + 1MB slack for zero-weight 64B fallback
    // windows that can run past the last group.
    const size_t need = (size_t)NBG * HWSZ * GC * sizeof(__half) + (1u << 20);
    if (ws_size >= need) {
        __half* pkh = (__half*)d_ws;
        repack_kernel<<<dim3(NBLK_RP), dim3(WW), 0, stream>>>(img, pkh);
        misc_filter_coop<<<dim3(NBLK_MAIN), dim3(256), 0, stream>>>(pkh, kv, kh, off, wgt, out);
    } else {
        misc_filter_direct<<<dim3(NBLK_RP), dim3(WW), 0, stream>>>(img, kv, kh, off, wgt, out);
    }
}

// Round 16
// 43.407 us; speedup vs baseline: 1.3934x; 1.3934x over previous
//
#include <hip/hip_runtime.h>
#include <hip/hip_fp16.h>

#define HH 256
#define WW 256
#define HWSZ (HH*WW)
#define CC 64
#define GG 4
#define GC 16
#define KK 3
#define PP 9
#define NB 2
#define NBG (NB*GG)            // 8 (b,g) slices
#define NBLK_RP (NBG*HH)       // 2048 repack blocks
#define NBLK_MAIN (NBG*1024)   // 8192 main blocks (16x4 pixel tile x 4 lanes)

typedef float f32x4 __attribute__((ext_vector_type(4)));

// ---------- Kernel 1: planar fp32 -> channels-last fp16 (per (b,g): [y][x][16]) ----------
__global__ __launch_bounds__(256) void repack_kernel(
    const float* __restrict__ img, __half* __restrict__ pk)
{
    int bid = blockIdx.x;
    int y  = bid & (HH - 1);
    int bg = bid >> 8;
    int g  = bg & (GG - 1);
    int b  = bg >> 2;
    int x  = threadIdx.x;

    const float* src = img + (size_t)(b*CC + g*GC) * HWSZ + y*WW + x;
    float v[GC];
#pragma unroll
    for (int c = 0; c < GC; ++c) v[c] = src[c*HWSZ];

    __half2 hh[8];
#pragma unroll
    for (int i = 0; i < 8; ++i) hh[i] = __floats2half2_rn(v[2*i], v[2*i+1]);

    uint4* dst = (uint4*)(pk + ((size_t)bg*HWSZ + y*WW + x) * GC);
    dst[0] = *(uint4*)&hh[0];
    dst[1] = *(uint4*)&hh[4];
}

// ---------- Kernel 2: fp16 row-pair gathers + LDS-dedup'd math ----------
// Final structure (r13): the wall is TA segment-lookup throughput (~2.1cyc
// per distinct 64B segment) with the 2.1MB/XCD packed slice L2-resident.
// fp16 pixel-groups (32B) make a tap's same-row corner pair one 64B load:
// 2 gather instrs/tap, ~3 segments/tap. Lanes q0,q1 = ch0-7/ch8-15 of group
// xb; q2,q3 = same of group xb+1. Boundary x folded into Phase-1 weights
// (zero-weight lanes may read 32B past the slice: ws has 1MB slack).
// shfl_xor(2) combines the two x-corner partial sums at the end.
// Falsified alternatives: fp32 scatter (r4-11, 2x segments), dup-pair 64B
// (r14: 2x footprint -> L2 thrash), LDS-staged region (r12/r15: LDS issue +
// swizzle VALU >= TA cost). launch_bounds stays (256,4): asm-load dest regs
// must not spill while in flight (round-7 failure at (256,8)).
__global__ __launch_bounds__(256, 4) void misc_filter_coop(
    const __half* __restrict__ pk,
    const float* __restrict__ kv,
    const float* __restrict__ kh,
    const float* __restrict__ off,
    const float* __restrict__ wgt,
    float* __restrict__ out)
{
    // XCD swizzle: 8192 blocks / 8 XCDs -> each XCD exactly one (b,g) slice.
    int phys = blockIdx.x;
    int logical = (phys & 7) * (NBLK_MAIN / 8) + (phys >> 3);
    int bg  = logical >> 10;          // 1024 tiles per (b,g)
    int blk = logical & 1023;
    int g   = bg & (GG - 1);
    int b   = bg >> 2;

    // 16x4 tile
    int tx = blk & 15;
    int ty = blk >> 4;
    const int tilebase = ty*4*WW + tx*16;

    int t  = threadIdx.x;

    __shared__ float Wlds[PP][64][4];   // folded lane weights
    __shared__ int   Olds[PP][64][2];   // row byte offsets (row0, row1)

    const float* offb = off + (size_t)(b*GG*PP*2 + g*PP*2) * HWSZ + tilebase;
    const float* wgtb = wgt + (size_t)(b*GG*PP   + g*PP  ) * HWSZ + tilebase;
    const float* khb  = kh  + (size_t)(b*GG*KK   + g*KK  ) * HWSZ + tilebase;
    const float* kvb  = kv  + (size_t)(b*KK) * HWSZ + tilebase;

    // ---- Phase 1: per-(pixel,tap) math, once, -> LDS ----
    for (int j = t; j < 64*PP; j += 256) {
        int pidx = j & 63;                  // pixel within tile
        int col  = j & 15;
        int row  = (j >> 4) & 3;
        int tap  = j >> 6;
        int kx   = (tap * 11) >> 5;         // tap/3 for tap<9
        int ky   = tap - 3*kx;
        int pixoff = row*WW + col;
        int pixel1 = tilebase + pixoff;
        int yy = pixel1 >> 8;
        int xx = pixel1 & (WW - 1);

        float ox  = offb[(2*tap  )*HWSZ + pixoff];
        float oy  = offb[(2*tap+1)*HWSZ + pixoff];
        float wv  = wgtb[tap*HWSZ + pixoff];
        float khv = khb[kx*HWSZ + pixoff];
        float kvv = kvb[ky*HWSZ + pixoff];
        float wp  = wv * (khv * kvv);

        float ux = (float)(xx + kx - 1) + ox;
        float uy = (float)(yy + ky - 1) + oy;
        float fx = floorf(ux), fy = floorf(uy);
        float wx = ux - fx,    wy = uy - fy;
        int x0 = (int)fx, y0 = (int)fy;
        int x1 = x0 + 1,  y1 = y0 + 1;
        bool vx0 = (unsigned)x0 < (unsigned)WW;
        bool vx1 = (unsigned)x1 < (unsigned)WW;
        bool vy0 = (unsigned)y0 < (unsigned)HH;
        bool vy1 = (unsigned)y1 < (unsigned)HH;

        // x side: base group xb and weights for groups xb, xb+1 (validity folded)
        float ql = vx0 ? (1.f - wx) : (vx1 ? wx : 0.f);
        float qr = (vx0 && vx1) ? wx : 0.f;
        int   xb = vx0 ? x0 : (vx1 ? x1 : 0);
        // y side
        float wy0 = vy0 ? (1.f - wy) : 0.f;
        float wy1 = vy1 ? wy : 0.f;
        int y0c = min(max(y0, 0), HH-1);
        int y1c = min(max(y1, 0), HH-1);

        *(float4*)&Wlds[tap][pidx][0] = make_float4(wy0*ql*wp, wy0*qr*wp,
                                                    wy1*ql*wp, wy1*qr*wp);
        *(int2*)&Olds[tap][pidx][0]   = make_int2((y0c*WW + xb)*32,
                                                  (y1c*WW + xb)*32);
    }
    __syncthreads();

    // ---- Phase 2: row-pair gathers + mixed fp16/fp32 FMA, depth-4 pipeline ----
    int q  = t & 3;                   // lane role: (x-side = q>>1, ch-half = q&1)
    int pi = t >> 2;                  // pixel within tile [0,64)
    int pixel = tilebase + (pi >> 4)*WW + (pi & 15);

    const __half* pkb = pk + (size_t)bg * HWSZ * GC;   // wave-uniform SGPR base
    const unsigned laneoff = (unsigned)q * 16u;        // 16B of the 64B row-pair

    float a0=0.f,a1=0.f,a2=0.f,a3=0.f,a4=0.f,a5=0.f,a6=0.f,a7=0.f;
    f32x4  wvb[2];        // LDS prefetch double-buffer: weights
    int2   ovb[2];        // LDS prefetch double-buffer: row offsets
    float  wA[4], wB[4];  // per-slot lane weights (row0, row1)
    uint4  vv[4][2];      // in-flight row data, 4-slot rotation

#define GLOAD(dst, boff) \
    asm volatile("global_load_dwordx4 %0, %1, %2" \
                 : "=v"(dst) : "v"(boff), "s"(pkb) : "memory")

#define WAITV(N) do { \
    asm volatile("s_waitcnt vmcnt(" #N ")" ::: "memory"); \
    __builtin_amdgcn_sched_barrier(0); } while (0)

#define LDSPREF(p) do { if ((p) < PP) {                                         \
    wvb[(p)&1] = *(const f32x4*)&Wlds[(p) < PP ? (p) : 0][pi][0];               \
    ovb[(p)&1] = *(const int2*)&Olds[(p) < PP ? (p) : 0][pi][0]; } } while (0)

#define TAP_L(p) do {                                                           \
    const int bi_ = (p) % 4;                                                    \
    f32x4 f_ = wvb[(p)&1];                                                      \
    wA[bi_] = (q & 2) ? f_[1] : f_[0];                                          \
    wB[bi_] = (q & 2) ? f_[3] : f_[2];                                          \
    int2 o_ = ovb[(p)&1];                                                       \
    GLOAD(vv[bi_][0], (unsigned)o_.x + laneoff);                                \
    GLOAD(vv[bi_][1], (unsigned)o_.y + laneoff);                                \
} while (0)

#define FMA8(u_, w_) do {                                                       \
    const __half2* h2_ = (const __half2*)&(u_);                                 \
    float2 f0_ = __half22float2(h2_[0]);                                        \
    float2 f1_ = __half22float2(h2_[1]);                                        \
    float2 f2_ = __half22float2(h2_[2]);                                        \
    float2 f3_ = __half22float2(h2_[3]);                                        \
    a0 = fmaf(f0_.x, (w_), a0); a1 = fmaf(f0_.y, (w_), a1);                     \
    a2 = fmaf(f1_.x, (w_), a2); a3 = fmaf(f1_.y, (w_), a3);                     \
    a4 = fmaf(f2_.x, (w_), a4); a5 = fmaf(f2_.y, (w_), a5);                     \
    a6 = fmaf(f3_.x, (w_), a6); a7 = fmaf(f3_.y, (w_), a7);                     \
} while (0)

#define TAP_FMA(p) do {                                                         \
    const int bi_ = (p) % 4;                                                    \
    FMA8(vv[bi_][0], wA[bi_]);                                                  \
    FMA8(vv[bi_][1], wB[bi_]);                                                  \
} while (0)

    // prologue: 4 taps x 2 loads = 8 in flight
    LDSPREF(0);
    LDSPREF(1); TAP_L(0);
    LDSPREF(2); TAP_L(1);
    LDSPREF(3); TAP_L(2);
    LDSPREF(4); TAP_L(3);
    // steady state
    LDSPREF(5); WAITV(6); TAP_FMA(0); TAP_L(4);
    LDSPREF(6); WAITV(6); TAP_FMA(1); TAP_L(5);
    LDSPREF(7); WAITV(6); TAP_FMA(2); TAP_L(6);
    LDSPREF(8); WAITV(6); TAP_FMA(3); TAP_L(7);
                WAITV(6); TAP_FMA(4); TAP_L(8);
    // drain
    WAITV(6); TAP_FMA(5);
    WAITV(4); TAP_FMA(6);
    WAITV(2); TAP_FMA(7);
    WAITV(0); TAP_FMA(8);

#undef GLOAD
#undef WAITV
#undef LDSPREF
#undef TAP_L
#undef FMA8
#undef TAP_FMA

    // combine x-corner partials: lanes q and q^2 hold the same 8 channels
    a0 += __shfl_xor(a0, 2); a1 += __shfl_xor(a1, 2);
    a2 += __shfl_xor(a2, 2); a3 += __shfl_xor(a3, 2);
    a4 += __shfl_xor(a4, 2); a5 += __shfl_xor(a5, 2);
    a6 += __shfl_xor(a6, 2); a7 += __shfl_xor(a7, 2);

    // lane q stores channels (q&1)*8 + (q&2?4:0) .. +4
    float* outp = out + (size_t)(b*CC + g*GC + (q&1)*8 + ((q&2)?4:0)) * HWSZ + pixel;
    if (q & 2) {
        outp[0*HWSZ] = a4; outp[1*HWSZ] = a5; outp[2*HWSZ] = a6; outp[3*HWSZ] = a7;
    } else {
        outp[0*HWSZ] = a0; outp[1*HWSZ] = a1; outp[2*HWSZ] = a2; outp[3*HWSZ] = a3;
    }
}

// ---------- Fallback: direct planar fp32 kernel (if ws too small) ----------
__global__ __launch_bounds__(256) void misc_filter_direct(
    const float* __restrict__ img,
    const float* __restrict__ kv,
    const float* __restrict__ kh,
    const float* __restrict__ off,
    const float* __restrict__ wgt,
    float* __restrict__ out)
{
    int phys = blockIdx.x;
    int logical = (phys & 7) * (NBLK_RP / 8) + (phys >> 3);
    int y  = logical & (HH - 1);
    int bg = logical >> 8;
    int g  = bg & (GG - 1);
    int b  = bg >> 2;
    int x  = threadIdx.x;

    const float* imgp = img + (size_t)(b*CC + g*GC) * HWSZ;
    int pix = y*WW + x;
    const float* offp = off + (size_t)(b*GG*PP*2 + g*PP*2) * HWSZ + pix;
    const float* wgtp = wgt + (size_t)(b*GG*PP   + g*PP  ) * HWSZ + pix;
    const float* khp  = kh  + (size_t)(b*GG*KK   + g*KK  ) * HWSZ + pix;
    const float* kvp  = kv  + (size_t)(b*KK) * HWSZ + pix;

    float khr[KK], kvr[KK];
#pragma unroll
    for (int i = 0; i < KK; ++i) { khr[i] = khp[i*HWSZ]; kvr[i] = kvp[i*HWSZ]; }
    float acc[GC];
#pragma unroll
    for (int c = 0; c < GC; ++c) acc[c] = 0.f;

#pragma unroll
    for (int p = 0; p < PP; ++p) {
        const int kx = p / KK, ky = p % KK;
        float ox = offp[(2*p  )*HWSZ];
        float oy = offp[(2*p+1)*HWSZ];
        float wp = wgtp[p*HWSZ] * khr[kx] * kvr[ky];
        float ux = (float)(x + kx - 1) + ox;
        float uy = (float)(y + ky - 1) + oy;
        float fx = floorf(ux), fy = floorf(uy);
        float wx = ux - fx,    wy = uy - fy;
        int x0 = (int)fx, y0 = (int)fy;
        int x1 = x0 + 1,  y1 = y0 + 1;
        bool vx0 = (unsigned)x0 < (unsigned)WW;
        bool vx1 = (unsigned)x1 < (unsigned)WW;
        bool vy0 = (unsigned)y0 < (unsigned)HH;
        bool vy1 = (unsigned)y1 < (unsigned)HH;
        float w00 = (1.f-wx)*(1.f-wy)*wp; if (!(vx0 && vy0)) w00 = 0.f;
        float w01 =      wx *(1.f-wy)*wp; if (!(vx1 && vy0)) w01 = 0.f;
        float w10 = (1.f-wx)*     wy *wp; if (!(vx0 && vy1)) w10 = 0.f;
        float w11 =      wx *     wy *wp; if (!(vx1 && vy1)) w11 = 0.f;
        int x0c = min(max(x0, 0), WW-1), x1c = min(max(x1, 0), WW-1);
        int y0c = min(max(y0, 0), HH-1), y1c = min(max(y1, 0), HH-1);
        int i00 = y0c*WW + x0c, i01 = y0c*WW + x1c;
        int i10 = y1c*WW + x0c, i11 = y1c*WW + x1c;
#pragma unroll
        for (int c = 0; c < GC; ++c) {
            const float* pl = imgp + c*HWSZ;
            acc[c] = fmaf(w00, pl[i00], acc[c]);
            acc[c] = fmaf(w01, pl[i01], acc[c]);
            acc[c] = fmaf(w10, pl[i10], acc[c]);
            acc[c] = fmaf(w11, pl[i11], acc[c]);
        }
    }
    float* outp = out + (size_t)(b*CC + g*GC) * HWSZ + pix;
#pragma unroll
    for (int c = 0; c < GC; ++c) outp[c*HWSZ] = acc[c];
}

extern "C" void kernel_launch(void* const* d_in, const int* in_sizes, int n_in,
                              void* d_out, int out_size, void* d_ws, size_t ws_size,
                              hipStream_t stream) {
    const float* img = (const float*)d_in[0];
    const float* kv  = (const float*)d_in[1];
    const float* kh  = (const float*)d_in[2];
    const float* off = (const float*)d_in[3];
    const float* wgt = (const float*)d_in[4];
    float* out = (float*)d_out;

    // fp16 packed slice = 16.8MB; require extra 1MB slack for zero-weight
    // row-pair reads that run past the last group.
    const size_t need = (size_t)NBG * HWSZ * GC * sizeof(__half) + (1u << 20);
    if (ws_size >= need) {
        __half* pkh = (__half*)d_ws;
        repack_kernel<<<dim3(NBLK_RP), dim3(WW), 0, stream>>>(img, pkh);
        misc_filter_coop<<<dim3(NBLK_MAIN), dim3(256), 0, stream>>>(pkh, kv, kh, off, wgt, out);
    } else {
        misc_filter_direct<<<dim3(NBLK_RP), dim3(WW), 0, stream>>>(img, kv, kh, off, wgt, out);
    }
}